// Round 5
// baseline (507.602 us; speedup 1.0000x reference)
//
#include <hip/hip_runtime.h>

// EncoderBlock: B=4 S=2048 D=1024 H=16 DK=64 DFF=4096
// R11: pipeline k_attention's kt loop (R10 recipe applied to attention).
//      R10 post-mortem: attention now L2-resident (FETCH 28MB, HBM 5%) but
//      no pipe >35% busy -> per-kt __syncthreads drain exposes K/V latency
//      32x. Changes (attention only):
//      - K/V double-buffered (ring-2): K via global_load_lds 1 tile ahead,
//        V reg-staged 1 tile ahead (T14 issue-early/write-late).
//      - raw s_barrier + counted s_waitcnt vmcnt(2) (window = exactly 2 vmem
//        issues: V dwordx4 + K DMA); never vmcnt(0) mid-loop.
//      - mask table staged to LDS once (8 KB prologue DMA): no per-kt vmem
//        in compute (keeps the vmcnt count exact), broadcast ds_reads free.
//      WAR: Ks[p] DMA(t+1) lands after end-barrier of compute(t-1) (last
//      reader); Vs[p] written at t, last read compute(t-2).
//      GEMM (R10 ring-3), LN, transposes unchanged.

typedef unsigned short u16;
typedef unsigned u32;
typedef __bf16 bf16x8 __attribute__((ext_vector_type(8)));
typedef float f32x4 __attribute__((ext_vector_type(4)));
typedef float f32x16 __attribute__((ext_vector_type(16)));

typedef __attribute__((address_space(1))) const void* as1_cvp;
typedef __attribute__((address_space(3))) void* as3_vp;

__device__ __forceinline__ void async_copy16(const void* g, void* l) {
  __builtin_amdgcn_global_load_lds((as1_cvp)g, (as3_vp)l, 16, 0, 0);
}

__device__ __forceinline__ u16 f2bf(float f) {
  unsigned u = __float_as_uint(f);
  u += 0x7fffu + ((u >> 16) & 1u);  // RNE
  return (u16)(u >> 16);
}

__device__ __forceinline__ float fast_exp2(float x) {
  return __builtin_amdgcn_exp2f(x);
}

__device__ __forceinline__ u32 cvt_pk_bf16(float lo, float hi) {
  u32 d;
  asm("v_cvt_pk_bf16_f32 %0, %1, %2" : "=v"(d) : "v"(lo), "v"(hi));
  return d;
}

// v_permlane32_swap_b32 x, y: x'.hi = y.lo, y'.lo = x.hi (lane&31 preserved)
__device__ __forceinline__ void permlane32_swap(u32& x, u32& y) {
  asm volatile("v_permlane32_swap_b32 %0, %1" : "+v"(x), "+v"(y));
}

// ---------- transpose fp32 [K,N] -> bf16 [N,K], optional scale ----------
__global__ __launch_bounds__(256) void k_transpose_bf16(
    const float* __restrict__ src, u16* __restrict__ dst, int K, int N,
    float scale) {
  __shared__ float tile[32][33];
  int n0 = blockIdx.x * 32, k0 = blockIdx.y * 32;
  int c = threadIdx.x & 31, r0 = threadIdx.x >> 5;
#pragma unroll
  for (int i = 0; i < 32; i += 8)
    tile[r0 + i][c] = src[(size_t)(k0 + r0 + i) * N + n0 + c];
  __syncthreads();
#pragma unroll
  for (int i = 0; i < 32; i += 8)
    dst[(size_t)(n0 + r0 + i) * K + k0 + c] = f2bf(tile[c][r0 + i] * scale);
}

// ---------- pack QKV bias (bq scaled) ----------
__global__ __launch_bounds__(256) void k_pack_bias(
    const float* __restrict__ bq, const float* __restrict__ bk,
    const float* __restrict__ bv, float* __restrict__ out, float qscale) {
  int i = blockIdx.x * 256 + threadIdx.x;
  float v;
  if (i < 1024) v = bq[i] * qscale;
  else if (i < 2048) v = bk[i - 1024];
  else v = bv[i - 2048];
  out[i] = v;
}

// ---------- mask -> additive f32 table (0 valid, -1e30 masked) ----------
__global__ __launch_bounds__(256) void k_maskadd(
    const int* __restrict__ mask, float* __restrict__ madd) {
  int i = blockIdx.x * 256 + threadIdx.x;
  madd[i] = mask[i] ? 0.0f : -1e30f;
}

// ---------- layernorm (ddof=1, /(std+eps)) -> bf16 ----------
__global__ __launch_bounds__(256) void k_layernorm_bf16(
    const float* __restrict__ x, const float* __restrict__ w,
    const float* __restrict__ b, u16* __restrict__ out) {
  const int D = 1024;
  int row = blockIdx.x, tid = threadIdx.x;
  const float4* xr = (const float4*)(x + (size_t)row * D);
  float4 v = xr[tid];
  float s = v.x + v.y + v.z + v.w;
  float ss = v.x * v.x + v.y * v.y + v.z * v.z + v.w * v.w;
#pragma unroll
  for (int off = 1; off < 64; off <<= 1) {
    s += __shfl_xor(s, off);
    ss += __shfl_xor(ss, off);
  }
  __shared__ float rs[4], rss[4];
  int wave = tid >> 6, lane = tid & 63;
  if (lane == 0) { rs[wave] = s; rss[wave] = ss; }
  __syncthreads();
  float S_ = rs[0] + rs[1] + rs[2] + rs[3];
  float SS = rss[0] + rss[1] + rss[2] + rss[3];
  float mean = S_ * (1.0f / D);
  float var = (SS - (float)D * mean * mean) * (1.0f / (D - 1));
  float inv = 1.0f / (sqrtf(fmaxf(var, 0.0f)) + 1e-6f);
  float4 wv = ((const float4*)w)[tid], bv = ((const float4*)b)[tid];
  u16* orow = out + (size_t)row * D + tid * 4;
  orow[0] = f2bf(wv.x * (v.x - mean) * inv + bv.x);
  orow[1] = f2bf(wv.y * (v.y - mean) * inv + bv.y);
  orow[2] = f2bf(wv.z * (v.z - mean) * inv + bv.z);
  orow[3] = f2bf(wv.w * (v.w - mean) * inv + bv.w);
}

// ---------- GEMM: C[M,N] = A[M,K]bf16 @ Bt[N,K]^T + bias (+res)(relu) -----
// (R10 ring-3 counted-vmcnt pipeline, unchanged.)
template <bool RELU, bool HAS_RES, bool OUT_BF16>
__global__ __launch_bounds__(512, 2) void k_gemm2(
    const u16* __restrict__ A, const u16* __restrict__ Bt,
    const float* __restrict__ bias, const float* __restrict__ res,
    void* __restrict__ outp, int M, int N, int K) {
  __shared__ __align__(16) u16 lds[3 * 24576];  // 144 KB
  const int tid = threadIdx.x;
  const int lane = tid & 63, wave = tid >> 6;
  const int quad = lane >> 4, l16 = lane & 15;
  const int m0 = blockIdx.x * 256, n0 = blockIdx.y * 128;
  const int wm = (wave >> 1) * 64, wn = (wave & 1) * 64;

  const int srow = tid >> 3;
  const int schunk8 = ((tid & 7) ^ (srow & 7)) * 8;
  const u16* gA0 = A + (size_t)(m0 + srow) * K + schunk8;
  const u16* gA1 = A + (size_t)(m0 + 64 + srow) * K + schunk8;
  const u16* gA2 = A + (size_t)(m0 + 128 + srow) * K + schunk8;
  const u16* gA3 = A + (size_t)(m0 + 192 + srow) * K + schunk8;
  const u16* gB0 = Bt + (size_t)(n0 + srow) * K + schunk8;
  const u16* gB1 = Bt + (size_t)(n0 + 64 + srow) * K + schunk8;

  auto STAGE = [&](int t, int s) {
    const size_t ko = (size_t)t * 64;
    u16* sb = lds + s * 24576;
    async_copy16(gA0 + ko, sb + tid * 8);
    async_copy16(gA1 + ko, sb + 4096 + tid * 8);
    async_copy16(gA2 + ko, sb + 8192 + tid * 8);
    async_copy16(gA3 + ko, sb + 12288 + tid * 8);
    async_copy16(gB0 + ko, sb + 16384 + tid * 8);
    async_copy16(gB1 + ko, sb + 20480 + tid * 8);
  };

  f32x4 zero = {0.0f, 0.0f, 0.0f, 0.0f};
  f32x4 acc[4][4];
#pragma unroll
  for (int i = 0; i < 4; i++)
#pragma unroll
    for (int j = 0; j < 4; j++) acc[i][j] = zero;

  STAGE(0, 0);
  STAGE(1, 1);
  const int NT = K >> 6;
  for (int t = 0; t < NT; t++) {
    asm volatile("s_waitcnt vmcnt(6)" ::: "memory");
    __builtin_amdgcn_s_barrier();
    if (t + 2 < NT) STAGE(t + 2, (t + 2) % 3);
    const u16* sb = lds + (t % 3) * 24576;
    const u16* sbB = sb + 16384;
#pragma unroll
    for (int ks = 0; ks < 2; ks++) {
      bf16x8 af[4], bfr[4];
#pragma unroll
      for (int mb = 0; mb < 4; mb++) {
        int R = wm + mb * 16 + l16;
        af[mb] = *(const bf16x8*)&sb[R * 64 + (((4 * ks + quad) ^ (R & 7)) * 8)];
      }
#pragma unroll
      for (int nb = 0; nb < 4; nb++) {
        int C = wn + nb * 16 + l16;
        bfr[nb] =
            *(const bf16x8*)&sbB[C * 64 + (((4 * ks + quad) ^ (C & 7)) * 8)];
      }
#pragma unroll
      for (int mb = 0; mb < 4; mb++)
#pragma unroll
        for (int nb = 0; nb < 4; nb++)
          acc[mb][nb] = __builtin_amdgcn_mfma_f32_16x16x32_bf16(
              af[mb], bfr[nb], acc[mb][nb], 0, 0, 0);
    }
  }
#pragma unroll
  for (int mb = 0; mb < 4; mb++) {
#pragma unroll
    for (int nb = 0; nb < 4; nb++) {
      int col = n0 + wn + nb * 16 + l16;
      float bb = bias[col];
#pragma unroll
      for (int r = 0; r < 4; r++) {
        int row = m0 + wm + mb * 16 + quad * 4 + r;
        float vv = acc[mb][nb][r] + bb;
        if (HAS_RES) vv += res[(size_t)row * N + col];
        if (RELU) vv = fmaxf(vv, 0.0f);
        if (OUT_BF16) ((u16*)outp)[(size_t)row * N + col] = f2bf(vv);
        else ((float*)outp)[(size_t)row * N + col] = vv;
      }
    }
  }
}

// ---------- flash attention, 512 threads, 256 q-rows, 40 KB LDS ----------
// R9 math/layouts unchanged; R11 adds ring-2 K/V double-buffer + counted
// vmcnt + raw barriers + mask-in-LDS (see file header).
__global__ __launch_bounds__(512, 4) void k_attention(
    const u16* __restrict__ qkv, const float* __restrict__ madd,
    u16* __restrict__ out) {
  const int S = 2048, D = 1024, QS = 3072;
  int blk = blockIdx.x;
  int xcd = blk & 7, t0 = blk >> 3;
  int qt = t0 & 7, gg = t0 >> 3;
  int g = gg * 8 + xcd;
  int h = g & 15, bb = g >> 4;
  int tid = threadIdx.x, lane = tid & 63, wave = tid >> 6;
  int l32 = lane & 31, hh = lane >> 5;

  __shared__ __align__(16) u16 Ks[2][64 * 64];
  __shared__ __align__(16) u16 Vs[2][64 * 64];
  __shared__ __align__(16) float Ms[2048];

  const int qrowbase = bb * S + qt * 256;
  const int sbase = bb * S;
  const int qrow = qrowbase + wave * 32 + l32;

  // Q fragments direct from global: 4x16B, all within one 128B line.
  bf16x8 qf[4];
  {
    const u16* qp = qkv + (size_t)qrow * QS + h * 64 + 8 * hh;
#pragma unroll
    for (int c = 0; c < 4; c++) qf[c] = *(const bf16x8*)(qp + 16 * c);
  }

  bf16x8 ones;
  {
    union { u16 s[8]; bf16x8 v; } o_;
#pragma unroll
    for (int j = 0; j < 8; j++) o_.s[j] = 0x3F80;  // bf16 1.0
    ones = o_.v;
  }

  f32x16 accA, accB, lacc;
#pragma unroll
  for (int r = 0; r < 16; r++) { accA[r] = 0.0f; accB[r] = 0.0f; lacc[r] = 0.0f; }

  // staging patterns
  const int krow = tid >> 3, ko = ((tid & 7) ^ (krow & 7)) * 8;
  const int vkey = tid >> 3, vf = tid & 7;

  uint4 vbc, vbn;

  // ---- prologue: tile 0 in flight + mask table to LDS ----
  vbc = *(const uint4*)(qkv + (size_t)(sbase + vkey) * QS + 2048 + h * 64 +
                        vf * 8);
  async_copy16(madd + sbase + tid * 4, Ms + tid * 4);
  async_copy16(qkv + (size_t)(sbase + krow) * QS + 1024 + h * 64 + ko,
               Ks[0] + tid * 8);

  auto STEP = [&](int t, u16* KsC, u16* KsN, u16* VsC, uint4& vbU, uint4& vbL,
                  bool last) {
    // issue tile t+1 (exactly 2 vmem ops in this window)
    if (!last) {
      const int nb0 = sbase + (t + 1) * 64;
      vbL = *(const uint4*)(qkv + (size_t)(nb0 + vkey) * QS + 2048 + h * 64 +
                            vf * 8);
      async_copy16(qkv + (size_t)(nb0 + krow) * QS + 1024 + h * 64 + ko,
                   KsN + tid * 8);
    }
    // V(t) regs -> LDS (compiler inserts precise wait on vbU)
    {
      union { uint4 u; u16 s[8]; } tv;
      tv.u = vbU;
#pragma unroll
      for (int j = 0; j < 8; j++)
        VsC[(8 * vf + j) * 64 + (vkey ^ (8 * (vf ^ j)))] = tv.s[j];
    }
    // tile t ready: own DMA landed (vmcnt leaves the 2 window-t issues in
    // flight), own ds_writes done (lgkmcnt 0); barrier -> all waves.
    if (!last) asm volatile("s_waitcnt vmcnt(2) lgkmcnt(0)" ::: "memory");
    else       asm volatile("s_waitcnt vmcnt(0) lgkmcnt(0)" ::: "memory");
    __builtin_amdgcn_s_barrier();

    // ---- compute on tile t ----
    u32 pa[4][4];
#pragma unroll
    for (int kb = 0; kb < 2; kb++) {
      const int kr = kb * 32 + l32;
      f32x16 sc;
#pragma unroll
      for (int r = 0; r < 16; r++) sc[r] = 0.0f;
#pragma unroll
      for (int c = 0; c < 4; c++) {
        bf16x8 kf =
            *(const bf16x8*)&KsC[kr * 64 + (((2 * c + hh) ^ (kr & 7)) * 8)];
        sc = __builtin_amdgcn_mfma_f32_32x32x16_bf16(kf, qf[c], sc, 0, 0, 0);
      }
      // mask from LDS (broadcast reads) + exp2, in place
      f32x4 mv0 = *(const f32x4*)&Ms[t * 64 + kb * 32 + 0 + 4 * hh];
      f32x4 mv1 = *(const f32x4*)&Ms[t * 64 + kb * 32 + 8 + 4 * hh];
      f32x4 mv2 = *(const f32x4*)&Ms[t * 64 + kb * 32 + 16 + 4 * hh];
      f32x4 mv3 = *(const f32x4*)&Ms[t * 64 + kb * 32 + 24 + 4 * hh];
#pragma unroll
      for (int r = 0; r < 4; r++) sc[r] = fast_exp2(sc[r] + mv0[r]);
#pragma unroll
      for (int r = 0; r < 4; r++) sc[4 + r] = fast_exp2(sc[4 + r] + mv1[r]);
#pragma unroll
      for (int r = 0; r < 4; r++) sc[8 + r] = fast_exp2(sc[8 + r] + mv2[r]);
#pragma unroll
      for (int r = 0; r < 4; r++) sc[12 + r] = fast_exp2(sc[12 + r] + mv3[r]);
      // P -> bf16 A-frags fully in-register (T12)
#pragma unroll
      for (int hk = 0; hk < 2; hk++) {
        u32 a0 = cvt_pk_bf16(sc[hk * 8 + 0], sc[hk * 8 + 1]);
        u32 a1 = cvt_pk_bf16(sc[hk * 8 + 2], sc[hk * 8 + 3]);
        u32 b0 = cvt_pk_bf16(sc[hk * 8 + 4], sc[hk * 8 + 5]);
        u32 b1 = cvt_pk_bf16(sc[hk * 8 + 6], sc[hk * 8 + 7]);
        permlane32_swap(a0, b0);
        permlane32_swap(a1, b1);
        pa[kb * 2 + hk][0] = a0;
        pa[kb * 2 + hk][1] = a1;
        pa[kb * 2 + hk][2] = b0;
        pa[kb * 2 + hk][3] = b1;
      }
    }
    // l accumulation (ones-MFMA) + PV, per 16-key chunk
#pragma unroll
    for (int kc = 0; kc < 4; kc++) {
      union { u32 u[4]; bf16x8 v; } pu;
      pu.u[0] = pa[kc][0]; pu.u[1] = pa[kc][1];
      pu.u[2] = pa[kc][2]; pu.u[3] = pa[kc][3];
      lacc = __builtin_amdgcn_mfma_f32_32x32x16_bf16(pu.v, ones, lacc, 0, 0, 0);
      const int kch = 2 * kc + hh;
      const int r0v = l32;
      bf16x8 v0 =
          *(const bf16x8*)&VsC[r0v * 64 + ((kch ^ (((r0v >> 3) ^ r0v) & 7)) * 8)];
      accA = __builtin_amdgcn_mfma_f32_32x32x16_bf16(pu.v, v0, accA, 0, 0, 0);
      const int r1v = 32 + l32;
      bf16x8 v1 =
          *(const bf16x8*)&VsC[r1v * 64 + ((kch ^ (((r1v >> 3) ^ r1v) & 7)) * 8)];
      accB = __builtin_amdgcn_mfma_f32_32x32x16_bf16(pu.v, v1, accB, 0, 0, 0);
    }
    // WAR: next window's K-DMA(t+2) targets KsC (read above) -> barrier.
    __builtin_amdgcn_s_barrier();
  };

#pragma unroll 1
  for (int tt = 0; tt < 16; tt++) {
    STEP(2 * tt, Ks[0], Ks[1], Vs[0], vbc, vbn, false);
    STEP(2 * tt + 1, Ks[1], Ks[0], Vs[1], vbn, vbc, tt == 15);
  }

  // epilogue: O[q][d] = acc/l ; q = (r&3)+8*(r>>2)+4*hh, d = db*32 + l32
#pragma unroll
  for (int r = 0; r < 16; r++) {
    float inv = 1.0f / lacc[r];
    size_t row =
        (size_t)(qrowbase + wave * 32 + (r & 3) + 8 * (r >> 2) + 4 * hh);
    u16* op = out + row * D + h * 64;
    op[l32] = f2bf(accA[r] * inv);
    op[32 + l32] = f2bf(accB[r] * inv);
  }
}

extern "C" void kernel_launch(void* const* d_in, const int* in_sizes, int n_in,
                              void* d_out, int out_size, void* d_ws,
                              size_t ws_size, hipStream_t stream) {
  const float* x    = (const float*)d_in[0];
  const int*   mask = (const int*)d_in[1];
  const float* wq = (const float*)d_in[2];   const float* bq = (const float*)d_in[3];
  const float* wk = (const float*)d_in[4];   const float* bk = (const float*)d_in[5];
  const float* wv = (const float*)d_in[6];   const float* bv = (const float*)d_in[7];
  const float* wo = (const float*)d_in[8];   const float* bo = (const float*)d_in[9];
  const float* w1 = (const float*)d_in[10];  const float* b1 = (const float*)d_in[11];
  const float* w2 = (const float*)d_in[12];  const float* b2 = (const float*)d_in[13];
  const float* ln1w = (const float*)d_in[14]; const float* ln1b = (const float*)d_in[15];
  const float* ln2w = (const float*)d_in[16]; const float* ln2b = (const float*)d_in[17];
  float* outp = (float*)d_out;

  // Workspace (MB): [0,6) wqkvT  [6,8) woT  [8,16) w1T  [16,24) w2T
  // [24,40) xn (ln1 -> attn-out -> ln2, sequential lifetimes)
  // [40,88) qkv / [40,104) hb alias (ffn1 out; qkv dead by then)
  // [88,~) bqkv, madd   [104,136) y1 fp32
  char* ws = (char*)d_ws;
  const size_t MB = 1024 * 1024;
  u16* wqkvT = (u16*)(ws + 0 * MB);
  u16* woT   = (u16*)(ws + 6 * MB);
  u16* w1T   = (u16*)(ws + 8 * MB);
  u16* w2T   = (u16*)(ws + 16 * MB);
  u16* xn    = (u16*)(ws + 24 * MB);
  u16* qkvb  = (u16*)(ws + 40 * MB);
  u16* hb    = (u16*)(ws + 40 * MB);   // alias
  float* bqkv = (float*)(ws + 88 * MB);
  float* madd = (float*)(ws + 88 * MB + 64 * 1024);
  float* y1  = (float*)(ws + 104 * MB);

  const float qscale = 0.125f * 1.44269504f;  // log2(e)/sqrt(DK)

  k_transpose_bf16<<<dim3(32, 32), 256, 0, stream>>>(wq, wqkvT, 1024, 1024, qscale);
  k_transpose_bf16<<<dim3(32, 32), 256, 0, stream>>>(wk, wqkvT + 1024 * 1024, 1024, 1024, 1.0f);
  k_transpose_bf16<<<dim3(32, 32), 256, 0, stream>>>(wv, wqkvT + 2048 * 1024, 1024, 1024, 1.0f);
  k_transpose_bf16<<<dim3(32, 32), 256, 0, stream>>>(wo, woT, 1024, 1024, 1.0f);
  k_transpose_bf16<<<dim3(128, 32), 256, 0, stream>>>(w1, w1T, 1024, 4096, 1.0f);
  k_transpose_bf16<<<dim3(32, 128), 256, 0, stream>>>(w2, w2T, 4096, 1024, 1.0f);
  k_pack_bias<<<12, 256, 0, stream>>>(bq, bk, bv, bqkv, qscale);
  k_maskadd<<<32, 256, 0, stream>>>(mask, madd);

  k_layernorm_bf16<<<8192, 256, 0, stream>>>(x, ln1w, ln1b, xn);

  k_gemm2<false, false, true><<<dim3(32, 24), 512, 0, stream>>>(
      xn, wqkvT, bqkv, nullptr, qkvb, 8192, 3072, 1024);

  k_attention<<<512, 512, 0, stream>>>(qkvb, madd, xn);

  dim3 go(32, 8);
  k_gemm2<false, true, false><<<go, 512, 0, stream>>>(xn, woT, bo, x, y1, 8192, 1024, 1024);

  k_layernorm_bf16<<<8192, 256, 0, stream>>>(y1, ln2w, ln2b, xn);

  k_gemm2<true, false, true><<<dim3(32, 32), 512, 0, stream>>>(
      xn, w1T, b1, nullptr, hb, 8192, 4096, 1024);

  k_gemm2<false, true, false><<<go, 512, 0, stream>>>(hb, w2T, b2, y1, outp, 8192, 1024, 4096);
}

// Round 7
// 482.644 us; speedup vs baseline: 1.0517x; 1.0517x over previous
//
#include <hip/hip_runtime.h>

// EncoderBlock: B=4 S=2048 D=1024 H=16 DK=64 DFF=4096
// R12b: identical to R12 (bench infra failed; no kernel verdict). Audited for
//      deadlock/OOB: uniform barriers, wave-uniform+lane*16 LDS DMA dests,
//      in-bounds rows, ~210 live VGPR < 256 budget.
// R12: attention LDS-traffic halving. R11 post-mortem: V reg-prefetch
//      spilled to scratch (WRITE_SIZE 23->114 MB) and the latency-pipeline
//      theory was refuted (MfmaUtil flat) -> real wall is per-CU LDS-pipe
//      instruction throughput (~340 LDS cyc/wave/kt vs 160 MFMA cyc).
//      Fix: 4 waves x 64 q-rows (256 thr, QBLK=256 unchanged): every K/V/mask
//      LDS fragment read is reused for TWO q-groups -> LDS reads per q-row
//      halve. Simple 2-barrier sync (R10-style, no reg-prefetch -> no spill),
//      __launch_bounds__(256,2) for ~210 live VGPRs. R9 math/layouts verbatim
//      (swapped QK^T, T12 cvt_pk+permlane, ones-MFMA denominator, K chunk
//      swizzle, V^T involution swizzle, mask-in-LDS, XCD-group remap).
//      GEMM (R10 ring-3 counted-vmcnt), LN, transposes unchanged.

typedef unsigned short u16;
typedef unsigned u32;
typedef __bf16 bf16x8 __attribute__((ext_vector_type(8)));
typedef float f32x4 __attribute__((ext_vector_type(4)));
typedef float f32x16 __attribute__((ext_vector_type(16)));

typedef __attribute__((address_space(1))) const void* as1_cvp;
typedef __attribute__((address_space(3))) void* as3_vp;

__device__ __forceinline__ void async_copy16(const void* g, void* l) {
  __builtin_amdgcn_global_load_lds((as1_cvp)g, (as3_vp)l, 16, 0, 0);
}

__device__ __forceinline__ u16 f2bf(float f) {
  unsigned u = __float_as_uint(f);
  u += 0x7fffu + ((u >> 16) & 1u);  // RNE
  return (u16)(u >> 16);
}

__device__ __forceinline__ float fast_exp2(float x) {
  return __builtin_amdgcn_exp2f(x);
}

__device__ __forceinline__ u32 cvt_pk_bf16(float lo, float hi) {
  u32 d;
  asm("v_cvt_pk_bf16_f32 %0, %1, %2" : "=v"(d) : "v"(lo), "v"(hi));
  return d;
}

// v_permlane32_swap_b32 x, y: x'.hi = y.lo, y'.lo = x.hi (lane&31 preserved)
__device__ __forceinline__ void permlane32_swap(u32& x, u32& y) {
  asm volatile("v_permlane32_swap_b32 %0, %1" : "+v"(x), "+v"(y));
}

// ---------- transpose fp32 [K,N] -> bf16 [N,K], optional scale ----------
__global__ __launch_bounds__(256) void k_transpose_bf16(
    const float* __restrict__ src, u16* __restrict__ dst, int K, int N,
    float scale) {
  __shared__ float tile[32][33];
  int n0 = blockIdx.x * 32, k0 = blockIdx.y * 32;
  int c = threadIdx.x & 31, r0 = threadIdx.x >> 5;
#pragma unroll
  for (int i = 0; i < 32; i += 8)
    tile[r0 + i][c] = src[(size_t)(k0 + r0 + i) * N + n0 + c];
  __syncthreads();
#pragma unroll
  for (int i = 0; i < 32; i += 8)
    dst[(size_t)(n0 + r0 + i) * K + k0 + c] = f2bf(tile[c][r0 + i] * scale);
}

// ---------- pack QKV bias (bq scaled) ----------
__global__ __launch_bounds__(256) void k_pack_bias(
    const float* __restrict__ bq, const float* __restrict__ bk,
    const float* __restrict__ bv, float* __restrict__ out, float qscale) {
  int i = blockIdx.x * 256 + threadIdx.x;
  float v;
  if (i < 1024) v = bq[i] * qscale;
  else if (i < 2048) v = bk[i - 1024];
  else v = bv[i - 2048];
  out[i] = v;
}

// ---------- mask -> additive f32 table (0 valid, -1e30 masked) ----------
__global__ __launch_bounds__(256) void k_maskadd(
    const int* __restrict__ mask, float* __restrict__ madd) {
  int i = blockIdx.x * 256 + threadIdx.x;
  madd[i] = mask[i] ? 0.0f : -1e30f;
}

// ---------- layernorm (ddof=1, /(std+eps)) -> bf16 ----------
__global__ __launch_bounds__(256) void k_layernorm_bf16(
    const float* __restrict__ x, const float* __restrict__ w,
    const float* __restrict__ b, u16* __restrict__ out) {
  const int D = 1024;
  int row = blockIdx.x, tid = threadIdx.x;
  const float4* xr = (const float4*)(x + (size_t)row * D);
  float4 v = xr[tid];
  float s = v.x + v.y + v.z + v.w;
  float ss = v.x * v.x + v.y * v.y + v.z * v.z + v.w * v.w;
#pragma unroll
  for (int off = 1; off < 64; off <<= 1) {
    s += __shfl_xor(s, off);
    ss += __shfl_xor(ss, off);
  }
  __shared__ float rs[4], rss[4];
  int wave = tid >> 6, lane = tid & 63;
  if (lane == 0) { rs[wave] = s; rss[wave] = ss; }
  __syncthreads();
  float S_ = rs[0] + rs[1] + rs[2] + rs[3];
  float SS = rss[0] + rss[1] + rss[2] + rss[3];
  float mean = S_ * (1.0f / D);
  float var = (SS - (float)D * mean * mean) * (1.0f / (D - 1));
  float inv = 1.0f / (sqrtf(fmaxf(var, 0.0f)) + 1e-6f);
  float4 wv = ((const float4*)w)[tid], bv = ((const float4*)b)[tid];
  u16* orow = out + (size_t)row * D + tid * 4;
  orow[0] = f2bf(wv.x * (v.x - mean) * inv + bv.x);
  orow[1] = f2bf(wv.y * (v.y - mean) * inv + bv.y);
  orow[2] = f2bf(wv.z * (v.z - mean) * inv + bv.z);
  orow[3] = f2bf(wv.w * (v.w - mean) * inv + bv.w);
}

// ---------- GEMM: C[M,N] = A[M,K]bf16 @ Bt[N,K]^T + bias (+res)(relu) -----
// (R10 ring-3 counted-vmcnt pipeline, unchanged.)
template <bool RELU, bool HAS_RES, bool OUT_BF16>
__global__ __launch_bounds__(512, 2) void k_gemm2(
    const u16* __restrict__ A, const u16* __restrict__ Bt,
    const float* __restrict__ bias, const float* __restrict__ res,
    void* __restrict__ outp, int M, int N, int K) {
  __shared__ __align__(16) u16 lds[3 * 24576];  // 144 KB
  const int tid = threadIdx.x;
  const int lane = tid & 63, wave = tid >> 6;
  const int quad = lane >> 4, l16 = lane & 15;
  const int m0 = blockIdx.x * 256, n0 = blockIdx.y * 128;
  const int wm = (wave >> 1) * 64, wn = (wave & 1) * 64;

  const int srow = tid >> 3;
  const int schunk8 = ((tid & 7) ^ (srow & 7)) * 8;
  const u16* gA0 = A + (size_t)(m0 + srow) * K + schunk8;
  const u16* gA1 = A + (size_t)(m0 + 64 + srow) * K + schunk8;
  const u16* gA2 = A + (size_t)(m0 + 128 + srow) * K + schunk8;
  const u16* gA3 = A + (size_t)(m0 + 192 + srow) * K + schunk8;
  const u16* gB0 = Bt + (size_t)(n0 + srow) * K + schunk8;
  const u16* gB1 = Bt + (size_t)(n0 + 64 + srow) * K + schunk8;

  auto STAGE = [&](int t, int s) {
    const size_t ko = (size_t)t * 64;
    u16* sb = lds + s * 24576;
    async_copy16(gA0 + ko, sb + tid * 8);
    async_copy16(gA1 + ko, sb + 4096 + tid * 8);
    async_copy16(gA2 + ko, sb + 8192 + tid * 8);
    async_copy16(gA3 + ko, sb + 12288 + tid * 8);
    async_copy16(gB0 + ko, sb + 16384 + tid * 8);
    async_copy16(gB1 + ko, sb + 20480 + tid * 8);
  };

  f32x4 zero = {0.0f, 0.0f, 0.0f, 0.0f};
  f32x4 acc[4][4];
#pragma unroll
  for (int i = 0; i < 4; i++)
#pragma unroll
    for (int j = 0; j < 4; j++) acc[i][j] = zero;

  STAGE(0, 0);
  STAGE(1, 1);
  const int NT = K >> 6;
  for (int t = 0; t < NT; t++) {
    asm volatile("s_waitcnt vmcnt(6)" ::: "memory");
    __builtin_amdgcn_s_barrier();
    if (t + 2 < NT) STAGE(t + 2, (t + 2) % 3);
    const u16* sb = lds + (t % 3) * 24576;
    const u16* sbB = sb + 16384;
#pragma unroll
    for (int ks = 0; ks < 2; ks++) {
      bf16x8 af[4], bfr[4];
#pragma unroll
      for (int mb = 0; mb < 4; mb++) {
        int R = wm + mb * 16 + l16;
        af[mb] = *(const bf16x8*)&sb[R * 64 + (((4 * ks + quad) ^ (R & 7)) * 8)];
      }
#pragma unroll
      for (int nb = 0; nb < 4; nb++) {
        int C = wn + nb * 16 + l16;
        bfr[nb] =
            *(const bf16x8*)&sbB[C * 64 + (((4 * ks + quad) ^ (C & 7)) * 8)];
      }
#pragma unroll
      for (int mb = 0; mb < 4; mb++)
#pragma unroll
        for (int nb = 0; nb < 4; nb++)
          acc[mb][nb] = __builtin_amdgcn_mfma_f32_16x16x32_bf16(
              af[mb], bfr[nb], acc[mb][nb], 0, 0, 0);
    }
  }
#pragma unroll
  for (int mb = 0; mb < 4; mb++) {
#pragma unroll
    for (int nb = 0; nb < 4; nb++) {
      int col = n0 + wn + nb * 16 + l16;
      float bb = bias[col];
#pragma unroll
      for (int r = 0; r < 4; r++) {
        int row = m0 + wm + mb * 16 + quad * 4 + r;
        float vv = acc[mb][nb][r] + bb;
        if (HAS_RES) vv += res[(size_t)row * N + col];
        if (RELU) vv = fmaxf(vv, 0.0f);
        if (OUT_BF16) ((u16*)outp)[(size_t)row * N + col] = f2bf(vv);
        else ((float*)outp)[(size_t)row * N + col] = vv;
      }
    }
  }
}

// ---------- flash attention, 256 threads, 256 q-rows, 24 KB LDS ----------
// 4 waves x 64 q-rows (2 q-groups of 32 each); K/V/mask LDS reads shared
// across both groups. R9 math/layouts verbatim; simple 2-barrier sync.
__global__ __launch_bounds__(256, 2) void k_attention(
    const u16* __restrict__ qkv, const float* __restrict__ madd,
    u16* __restrict__ out) {
  const int S = 2048, D = 1024, QS = 3072;
  int blk = blockIdx.x;
  int xcd = blk & 7, t0 = blk >> 3;
  int qt = t0 & 7, gg = t0 >> 3;
  int g = gg * 8 + xcd;
  int h = g & 15, bb = g >> 4;
  int tid = threadIdx.x, lane = tid & 63, wave = tid >> 6;
  int l32 = lane & 31, hh = lane >> 5;

  __shared__ __align__(16) u16 Ks[64 * 64];
  __shared__ __align__(16) u16 Vs[64 * 64];
  __shared__ __align__(16) float Ms[2048];

  const int qrowbase = bb * S + qt * 256;
  const int sbase = bb * S;

  // Q frags for the wave's two q-groups (rows wave*64+l32 and +32).
  bf16x8 qf0[4], qf1[4];
  {
    const u16* qp0 =
        qkv + (size_t)(qrowbase + wave * 64 + l32) * QS + h * 64 + 8 * hh;
    const u16* qp1 = qp0 + (size_t)32 * QS;
#pragma unroll
    for (int c = 0; c < 4; c++) {
      qf0[c] = *(const bf16x8*)(qp0 + 16 * c);
      qf1[c] = *(const bf16x8*)(qp1 + 16 * c);
    }
  }

  bf16x8 ones;
  {
    union { u16 s[8]; bf16x8 v; } o_;
#pragma unroll
    for (int j = 0; j < 8; j++) o_.s[j] = 0x3F80;  // bf16 1.0
    ones = o_.v;
  }

  f32x16 accA0, accB0, lacc0, accA1, accB1, lacc1;
#pragma unroll
  for (int r = 0; r < 16; r++) {
    accA0[r] = 0.0f; accB0[r] = 0.0f; lacc0[r] = 0.0f;
    accA1[r] = 0.0f; accB1[r] = 0.0f; lacc1[r] = 0.0f;
  }

  // staging patterns (2 jobs/thread at 256 threads)
  // mask: once, 2 x 16B per thread
  async_copy16(madd + sbase + tid * 4, (float*)Ms + tid * 4);
  async_copy16(madd + sbase + (tid + 256) * 4, (float*)Ms + (tid + 256) * 4);

#pragma unroll 1
  for (int kt = 0; kt < 32; kt++) {
    const int kb0 = sbase + kt * 64;
    __syncthreads();  // WAR: previous iteration's readers done
    // K DMA: jobs c = tid, tid+256
#pragma unroll
    for (int s = 0; s < 2; s++) {
      int c = tid + s * 256;
      int krow = c >> 3, ko = ((c & 7) ^ (krow & 7)) * 8;
      async_copy16(qkv + (size_t)(kb0 + krow) * QS + 1024 + h * 64 + ko,
                   Ks + c * 8);
    }
    // V^T staged with involution swizzle: jobs j = tid, tid+256
#pragma unroll
    for (int s = 0; s < 2; s++) {
      int jb = tid + s * 256;
      int vkey = jb >> 3, vf = jb & 7;
      union { uint4 u; u16 s16[8]; } tt;
      tt.u = *(const uint4*)(qkv + (size_t)(kb0 + vkey) * QS + 2048 + h * 64 +
                             vf * 8);
#pragma unroll
      for (int j = 0; j < 8; j++)
        Vs[(8 * vf + j) * 64 + (vkey ^ (8 * (vf ^ j)))] = tt.s16[j];
    }
    __syncthreads();  // drain K-DMA (+mask on kt=0) + V stores

#pragma unroll
    for (int kb = 0; kb < 2; kb++) {
      const int kr = kb * 32 + l32;
      bf16x8 kf[4];
#pragma unroll
      for (int c = 0; c < 4; c++)
        kf[c] = *(const bf16x8*)&Ks[kr * 64 + (((2 * c + hh) ^ (kr & 7)) * 8)];
      f32x16 s0, s1;
#pragma unroll
      for (int r = 0; r < 16; r++) { s0[r] = 0.0f; s1[r] = 0.0f; }
#pragma unroll
      for (int c = 0; c < 4; c++) {
        s0 = __builtin_amdgcn_mfma_f32_32x32x16_bf16(kf[c], qf0[c], s0, 0, 0, 0);
        s1 = __builtin_amdgcn_mfma_f32_32x32x16_bf16(kf[c], qf1[c], s1, 0, 0, 0);
      }
      // mask (shared LDS broadcast reads) + exp2 for both groups
#pragma unroll
      for (int m = 0; m < 4; m++) {
        f32x4 mv = *(const f32x4*)&Ms[kt * 64 + kb * 32 + m * 8 + 4 * hh];
#pragma unroll
        for (int r = 0; r < 4; r++) {
          s0[m * 4 + r] = fast_exp2(s0[m * 4 + r] + mv[r]);
          s1[m * 4 + r] = fast_exp2(s1[m * 4 + r] + mv[r]);
        }
      }
      // P -> bf16 A-frags (T12) + fused lacc/PV per 16-key chunk
#pragma unroll
      for (int hk = 0; hk < 2; hk++) {
        u32 a0 = cvt_pk_bf16(s0[hk * 8 + 0], s0[hk * 8 + 1]);
        u32 a1 = cvt_pk_bf16(s0[hk * 8 + 2], s0[hk * 8 + 3]);
        u32 b0 = cvt_pk_bf16(s0[hk * 8 + 4], s0[hk * 8 + 5]);
        u32 b1 = cvt_pk_bf16(s0[hk * 8 + 6], s0[hk * 8 + 7]);
        permlane32_swap(a0, b0);
        permlane32_swap(a1, b1);
        union { u32 u[4]; bf16x8 v; } p0;
        p0.u[0] = a0; p0.u[1] = a1; p0.u[2] = b0; p0.u[3] = b1;
        u32 c0 = cvt_pk_bf16(s1[hk * 8 + 0], s1[hk * 8 + 1]);
        u32 c1 = cvt_pk_bf16(s1[hk * 8 + 2], s1[hk * 8 + 3]);
        u32 d0 = cvt_pk_bf16(s1[hk * 8 + 4], s1[hk * 8 + 5]);
        u32 d1 = cvt_pk_bf16(s1[hk * 8 + 6], s1[hk * 8 + 7]);
        permlane32_swap(c0, d0);
        permlane32_swap(c1, d1);
        union { u32 u[4]; bf16x8 v; } p1;
        p1.u[0] = c0; p1.u[1] = c1; p1.u[2] = d0; p1.u[3] = d1;

        const int kc = kb * 2 + hk;
        const int kch = 2 * kc + hh;
        lacc0 = __builtin_amdgcn_mfma_f32_32x32x16_bf16(p0.v, ones, lacc0, 0, 0, 0);
        lacc1 = __builtin_amdgcn_mfma_f32_32x32x16_bf16(p1.v, ones, lacc1, 0, 0, 0);
        const int r0v = l32;
        bf16x8 v0 = *(const bf16x8*)&Vs[r0v * 64 +
                                        ((kch ^ (((r0v >> 3) ^ r0v) & 7)) * 8)];
        accA0 = __builtin_amdgcn_mfma_f32_32x32x16_bf16(p0.v, v0, accA0, 0, 0, 0);
        accA1 = __builtin_amdgcn_mfma_f32_32x32x16_bf16(p1.v, v0, accA1, 0, 0, 0);
        const int r1v = 32 + l32;
        bf16x8 v1 = *(const bf16x8*)&Vs[r1v * 64 +
                                        ((kch ^ (((r1v >> 3) ^ r1v) & 7)) * 8)];
        accB0 = __builtin_amdgcn_mfma_f32_32x32x16_bf16(p0.v, v1, accB0, 0, 0, 0);
        accB1 = __builtin_amdgcn_mfma_f32_32x32x16_bf16(p1.v, v1, accB1, 0, 0, 0);
      }
    }
  }

  // epilogue: O[q][d] = acc/l ; q = (r&3)+8*(r>>2)+4*hh, d = db*32 + l32
#pragma unroll
  for (int r = 0; r < 16; r++) {
    float i0 = 1.0f / lacc0[r];
    float i1 = 1.0f / lacc1[r];
    size_t row0 =
        (size_t)(qrowbase + wave * 64 + (r & 3) + 8 * (r >> 2) + 4 * hh);
    u16* op0 = out + row0 * D + h * 64;
    op0[l32] = f2bf(accA0[r] * i0);
    op0[32 + l32] = f2bf(accB0[r] * i0);
    u16* op1 = op0 + (size_t)32 * D;
    op1[l32] = f2bf(accA1[r] * i1);
    op1[32 + l32] = f2bf(accB1[r] * i1);
  }
}

extern "C" void kernel_launch(void* const* d_in, const int* in_sizes, int n_in,
                              void* d_out, int out_size, void* d_ws,
                              size_t ws_size, hipStream_t stream) {
  const float* x    = (const float*)d_in[0];
  const int*   mask = (const int*)d_in[1];
  const float* wq = (const float*)d_in[2];   const float* bq = (const float*)d_in[3];
  const float* wk = (const float*)d_in[4];   const float* bk = (const float*)d_in[5];
  const float* wv = (const float*)d_in[6];   const float* bv = (const float*)d_in[7];
  const float* wo = (const float*)d_in[8];   const float* bo = (const float*)d_in[9];
  const float* w1 = (const float*)d_in[10];  const float* b1 = (const float*)d_in[11];
  const float* w2 = (const float*)d_in[12];  const float* b2 = (const float*)d_in[13];
  const float* ln1w = (const float*)d_in[14]; const float* ln1b = (const float*)d_in[15];
  const float* ln2w = (const float*)d_in[16]; const float* ln2b = (const float*)d_in[17];
  float* outp = (float*)d_out;

  // Workspace (MB): [0,6) wqkvT  [6,8) woT  [8,16) w1T  [16,24) w2T
  // [24,40) xn (ln1 -> attn-out -> ln2, sequential lifetimes)
  // [40,88) qkv / [40,104) hb alias (ffn1 out; qkv dead by then)
  // [88,~) bqkv, madd   [104,136) y1 fp32
  char* ws = (char*)d_ws;
  const size_t MB = 1024 * 1024;
  u16* wqkvT = (u16*)(ws + 0 * MB);
  u16* woT   = (u16*)(ws + 6 * MB);
  u16* w1T   = (u16*)(ws + 8 * MB);
  u16* w2T   = (u16*)(ws + 16 * MB);
  u16* xn    = (u16*)(ws + 24 * MB);
  u16* qkvb  = (u16*)(ws + 40 * MB);
  u16* hb    = (u16*)(ws + 40 * MB);   // alias
  float* bqkv = (float*)(ws + 88 * MB);
  float* madd = (float*)(ws + 88 * MB + 64 * 1024);
  float* y1  = (float*)(ws + 104 * MB);

  const float qscale = 0.125f * 1.44269504f;  // log2(e)/sqrt(DK)

  k_transpose_bf16<<<dim3(32, 32), 256, 0, stream>>>(wq, wqkvT, 1024, 1024, qscale);
  k_transpose_bf16<<<dim3(32, 32), 256, 0, stream>>>(wk, wqkvT + 1024 * 1024, 1024, 1024, 1.0f);
  k_transpose_bf16<<<dim3(32, 32), 256, 0, stream>>>(wv, wqkvT + 2048 * 1024, 1024, 1024, 1.0f);
  k_transpose_bf16<<<dim3(32, 32), 256, 0, stream>>>(wo, woT, 1024, 1024, 1.0f);
  k_transpose_bf16<<<dim3(128, 32), 256, 0, stream>>>(w1, w1T, 1024, 4096, 1.0f);
  k_transpose_bf16<<<dim3(32, 128), 256, 0, stream>>>(w2, w2T, 4096, 1024, 1.0f);
  k_pack_bias<<<12, 256, 0, stream>>>(bq, bk, bv, bqkv, qscale);
  k_maskadd<<<32, 256, 0, stream>>>(mask, madd);

  k_layernorm_bf16<<<8192, 256, 0, stream>>>(x, ln1w, ln1b, xn);

  k_gemm2<false, false, true><<<dim3(32, 24), 512, 0, stream>>>(
      xn, wqkvT, bqkv, nullptr, qkvb, 8192, 3072, 1024);

  k_attention<<<512, 256, 0, stream>>>(qkvb, madd, xn);

  dim3 go(32, 8);
  k_gemm2<false, true, false><<<go, 512, 0, stream>>>(xn, woT, bo, x, y1, 8192, 1024, 1024);

  k_layernorm_bf16<<<8192, 256, 0, stream>>>(y1, ln2w, ln2b, xn);

  k_gemm2<true, false, true><<<dim3(32, 32), 512, 0, stream>>>(
      xn, w1T, b1, nullptr, hb, 8192, 4096, 1024);

  k_gemm2<false, true, false><<<go, 512, 0, stream>>>(hb, w2T, b2, y1, outp, 8192, 1024, 4096);
}